// Round 12
// baseline (168.080 us; speedup 1.0000x reference)
//
#include <hip/hip_runtime.h>
#include <hip/hip_bf16.h>

typedef __attribute__((ext_vector_type(8))) short short8;
typedef __attribute__((ext_vector_type(4))) float f32x4;
typedef __attribute__((ext_vector_type(4))) unsigned int u32x4;

struct XPtrs { const float* p[17]; };
struct Bases { int v[18]; };

#define UROWS 32   // rows per unit (one unit per phase, 2 phases per block)

__device__ __forceinline__ unsigned short f2bf(float f) {
  unsigned u = __float_as_uint(f);
  return (unsigned short)((u + 0x7fffu + ((u >> 16) & 1u)) >> 16);  // RNE
}

// ---------------- pre-kernel: W fp32 -> bf16, fragment-packed into ws ----
// Per diag d: 2048 slots of 16 B. slot = sg*128 + n  (sg = s*4 + g)
// slot holds W[d][n][k] for k = sg*8 .. sg*8+7 as 8 bf16 (RNE).
__global__ __launch_bounds__(1024) void convert_w_kernel(
    const float* __restrict__ W, unsigned short* __restrict__ ws) {
  const int tid = blockIdx.x * 1024 + threadIdx.x;  // 0 .. 17*2048-1
  const int d  = tid >> 11;
  const int s2 = tid & 2047;
  const int sg = s2 >> 7;     // 0..15
  const int n  = s2 & 127;
  const float* src = W + ((size_t)d * 128 + n) * 128 + sg * 8;
  float4 a = *(const float4*)(src);
  float4 b = *(const float4*)(src + 4);
  unsigned u0 = (unsigned)f2bf(a.x) | ((unsigned)f2bf(a.y) << 16);
  unsigned u1 = (unsigned)f2bf(a.z) | ((unsigned)f2bf(a.w) << 16);
  unsigned u2 = (unsigned)f2bf(b.x) | ((unsigned)f2bf(b.y) << 16);
  unsigned u3 = (unsigned)f2bf(b.z) | ((unsigned)f2bf(b.w) << 16);
  *(uint4*)(ws + (size_t)tid * 8) = make_uint4(u0, u1, u2, u3);
}

// pack two fp32 -> u32 of two bf16, round-half-up (cheap; for X)
__device__ __forceinline__ unsigned pack_bf2(float lo, float hi) {
  unsigned rl = __float_as_uint(lo) + 0x8000u;
  unsigned rh = __float_as_uint(hi) + 0x8000u;
  return __builtin_amdgcn_perm(rh, rl, 0x07060302u);  // {rh[31:16], rl[31:16]}
}

__device__ __forceinline__ void issue_unit_loads(
    const float* __restrict__ x, int u, int wave, int lr, int lg,
    float4 (&pf)[8]) {
  const float* xr = x + ((size_t)(u * UROWS + wave * 16 + lr)) * 128 + lg * 8;
#pragma unroll
  for (int s = 0; s < 4; ++s) {
    pf[2 * s]     = *(const float4*)(xr + s * 32);
    pf[2 * s + 1] = *(const float4*)(xr + s * 32 + 4);
  }
}

__device__ __forceinline__ void convert_unit(const float4 (&pf)[8],
                                             short8 (&xf)[4]) {
#pragma unroll
  for (int s = 0; s < 4; ++s) {
    float4 a0 = pf[2 * s], a1 = pf[2 * s + 1];
    u32x4 w;
    w.x = pack_bf2(a0.x, a0.y);
    w.y = pack_bf2(a0.z, a0.w);
    w.z = pack_bf2(a1.x, a1.y);
    w.w = pack_bf2(a1.z, a1.w);
    xf[s] = __builtin_bit_cast(short8, w);
  }
}

// compute + store one 32-row unit against this block's 64-cout half.
// nb-outer, s-inner; store acc[nb] right after its 4 MFMAs (1 acc live).
__device__ __forceinline__ void compute_store_unit(
    const short8 (&xf)[4], const unsigned short* __restrict__ wlds,
    const float* __restrict__ blds, int u, int ch, int wave, int lr, int lg,
    int L, int start, int d, float* __restrict__ out) {
  const int f = u * UROWS + wave * 16 + lr;
  const unsigned b = (unsigned)f / (unsigned)L;
  const int l = f - (int)b * L;
  float* orow = out + (size_t)b * 10368 + (size_t)(start * 8 + d) * 128
                + (size_t)l * 1024 + ch * 64 + lg * 4;
#pragma unroll
  for (int nb = 0; nb < 4; ++nb) {
    f32x4 acc = *(const f32x4*)&blds[nb * 16 + lg * 4];   // bias init (LDS)
#pragma unroll
    for (int s = 0; s < 4; ++s) {
      short8 wf = *(const short8*)
          &wlds[(size_t)((s * 4 + lg) * 64 + nb * 16 + lr) * 8];
      acc = __builtin_amdgcn_mfma_f32_16x16x32_bf16(wf, xf[s], acc, 0, 0, 0);
    }
    *(f32x4*)(orow + nb * 16) = acc;
  }
}

// ---------------- main kernel ----------------
// 128 threads = 2 waves. Block owns HALF the couts (ch*64..ch*64+63, W half
// = 16 KiB LDS -> 8 blocks/CU) x 2 units of 32 rows in ONE diagonal.
// Prologue: W-half (8-9 global_load_lds, oldest in queue) then BOTH units'
// X loads to registers; barrier waits vmcnt(16) -> W resident, X in flight.
// 8 independent 2-wave blocks per CU decorrelate load-issue phases.
__global__ __launch_bounds__(128) void diag_linear_kernel(
    XPtrs xp, Bases bb, const unsigned short* __restrict__ wsrc,
    const float* __restrict__ bias, float* __restrict__ out) {
  const int bid = blockIdx.x;
  int d = 0;
#pragma unroll
  for (int i = 1; i < 17; ++i) d += (bid >= bb.v[i]) ? 1 : 0;
  const int L = 9 - ((d < 8) ? (8 - d) : (d - 8));
  const int start = (d > 8) ? (d - 8) : 0;
  const float* __restrict__ x = xp.p[d];
  const int bl = bid - bb.v[d];
  const int ch = bl & 1;           // cout half (adjacent bids share rows ->
  const int u0 = (bl >> 1) * 2;    //  second X read is L2/L3-hot)

  const int t = threadIdx.x;       // 0..127
  const int lane = t & 63;
  const int wave = t >> 6;         // 0..1
  const int lr = lane & 15;
  const int lg = lane >> 4;

  __shared__ unsigned short wlds[1024 * 8];  // 16 KiB: slot = sg*64 + n_local
  __shared__ float blds[64];                 // bias half

  // ---- stage W[d] half (pre-packed bf16) + bias via async global->LDS ----
  {
    const unsigned short* gw = wsrc + (size_t)d * 16384;
    typedef const __attribute__((address_space(1))) unsigned int* gas_u32;
    typedef __attribute__((address_space(3))) unsigned int* las_u32;
#pragma unroll
    for (int r = 0; r < 8; ++r) {
      const int sg = wave * 8 + r;                  // 0..15
      const int gslot = sg * 128 + ch * 64 + lane;  // contiguous 64-slot run
      const int lslot = sg * 64;                    // LDS base (lane-linear)
      __builtin_amdgcn_global_load_lds(
          (gas_u32)(const void*)(gw + (size_t)gslot * 8),
          (las_u32)(void*)(wlds + (size_t)lslot * 8),
          16, 0, 0);
    }
    if (t < 16) {  // lanes 0..15 -> blds[0..63], 16B/lane
      __builtin_amdgcn_global_load_lds(
          (gas_u32)(const void*)(bias + d * 128 + ch * 64 + t * 4),
          (las_u32)(void*)(blds), 16, 0, 0);
    }
  }

  // ---- both units' X loads into registers (stay in flight across barrier)
  float4 pA[8], pB[8];
  issue_unit_loads(x, u0,     wave, lr, lg, pA);
  issue_unit_loads(x, u0 + 1, wave, lr, lg, pB);

  // ---- barrier that does NOT drain the X loads ----
  asm volatile("s_waitcnt vmcnt(16)" ::: "memory");   // W + bias resident
  __builtin_amdgcn_s_barrier();
  __builtin_amdgcn_sched_barrier(0);                  // rule #18 fence

  // ---- phase A: unit u0 ----
  {
    short8 xf[4];
    convert_unit(pA, xf);   // compiler-inserted vmcnt waits for pA only
    compute_store_unit(xf, wlds, blds, u0, ch, wave, lr, lg, L, start, d, out);
  }
  // ---- phase B: unit u0+1 ----
  {
    short8 xf[4];
    convert_unit(pB, xf);
    compute_store_unit(xf, wlds, blds, u0 + 1, ch, wave, lr, lg, L, start, d, out);
  }
}

extern "C" void kernel_launch(void* const* d_in, const int* in_sizes, int n_in,
                              void* d_out, int out_size, void* d_ws, size_t ws_size,
                              hipStream_t stream) {
  const float* W = (const float*)d_in[0];
  const float* bias = (const float*)d_in[1];
  XPtrs xp;
  for (int i = 0; i < 17; ++i) xp.p[i] = (const float*)d_in[2 + i];
  float* out = (float*)d_out;
  unsigned short* ws = (unsigned short*)d_ws;   // 17*2048*16 B = 544 KiB

  Bases bb;
  int base = 0;
  for (int i = 0; i < 17; ++i) {
    bb.v[i] = base;
    int L = 9 - ((i < 8) ? (8 - i) : (i - 8));
    // rows = 8192*L; units of 32 rows = 256*L; x2 cout halves / 2 units per
    // block = 256*L blocks per diag
    base += 256 * L;
  }
  bb.v[17] = base;               // 256*81 = 20736 blocks

  convert_w_kernel<<<34, 1024, 0, stream>>>(W, ws);
  diag_linear_kernel<<<base, 128, 0, stream>>>(xp, bb, ws, bias, out);
}

// Round 13
// 146.208 us; speedup vs baseline: 1.1496x; 1.1496x over previous
//
#include <hip/hip_runtime.h>
#include <hip/hip_bf16.h>

typedef __attribute__((ext_vector_type(8))) short short8;
typedef __attribute__((ext_vector_type(4))) float f32x4;
typedef __attribute__((ext_vector_type(4))) unsigned int u32x4;

struct XPtrs { const float* p[17]; };
struct Bases { int v[18]; };

__device__ __forceinline__ unsigned short f2bf(float f) {
  unsigned u = __float_as_uint(f);
  return (unsigned short)((u + 0x7fffu + ((u >> 16) & 1u)) >> 16);  // RNE
}

// ---------------- pre-kernel: W fp32 -> bf16, fragment-packed into ws ----
// Per diag d: 2048 slots of 16 B. slot = sg*128 + n  (sg = s*4 + g)
// slot holds W[d][n][k] for k = sg*8 .. sg*8+7 as 8 bf16 (RNE).
__global__ __launch_bounds__(1024) void convert_w_kernel(
    const float* __restrict__ W, unsigned short* __restrict__ ws) {
  const int tid = blockIdx.x * 1024 + threadIdx.x;  // 0 .. 17*2048-1
  const int d  = tid >> 11;
  const int s2 = tid & 2047;
  const int sg = s2 >> 7;     // 0..15
  const int n  = s2 & 127;
  const float* src = W + ((size_t)d * 128 + n) * 128 + sg * 8;
  float4 a = *(const float4*)(src);
  float4 b = *(const float4*)(src + 4);
  unsigned u0 = (unsigned)f2bf(a.x) | ((unsigned)f2bf(a.y) << 16);
  unsigned u1 = (unsigned)f2bf(a.z) | ((unsigned)f2bf(a.w) << 16);
  unsigned u2 = (unsigned)f2bf(b.x) | ((unsigned)f2bf(b.y) << 16);
  unsigned u3 = (unsigned)f2bf(b.z) | ((unsigned)f2bf(b.w) << 16);
  *(uint4*)(ws + (size_t)tid * 8) = make_uint4(u0, u1, u2, u3);
}

// pack two fp32 -> u32 of two bf16, round-half-up (cheap; for X)
__device__ __forceinline__ unsigned pack_bf2(float lo, float hi) {
  unsigned rl = __float_as_uint(lo) + 0x8000u;
  unsigned rh = __float_as_uint(hi) + 0x8000u;
  return __builtin_amdgcn_perm(rh, rl, 0x07060302u);  // {rh[31:16], rl[31:16]}
}

// ---------------- main kernel ----------------
// 512 threads = 8 waves, ONE 128-row unit per block (16 rows/wave), CPB=1.
// Minimal VGPR (single pf buffer, store-interleaved epilogue) so regalloc
// lands <=85 -> 6 waves/SIMD -> 3 blocks/CU = 24 waves/CU. Latency hiding
// comes from block-level TLP (24 independent waves/CU), not intra-block
// pipelining. Non-draining vmcnt(8) barrier keeps pf in flight.
__global__ __launch_bounds__(512) void diag_linear_kernel(
    XPtrs xp, Bases bb, const unsigned short* __restrict__ wsrc,
    const float* __restrict__ bias, float* __restrict__ out) {
  const int bid = blockIdx.x;
  int d = 0;
#pragma unroll
  for (int i = 1; i < 17; ++i) d += (bid >= bb.v[i]) ? 1 : 0;
  const int L = 9 - ((d < 8) ? (8 - d) : (d - 8));
  const int start = (d > 8) ? (d - 8) : 0;
  const float* __restrict__ x = xp.p[d];
  const int u0 = bid - bb.v[d];     // unit index (128 rows per unit)

  const int t = threadIdx.x;        // 0..511
  const int lane = t & 63;
  const int wave = t >> 6;          // 0..7
  const int lr = lane & 15;
  const int lg = lane >> 4;

  __shared__ unsigned short wlds[2048 * 8];  // 32 KiB
  __shared__ float blds[128];                // bias

  // ---- stage W[d] (pre-packed bf16) + bias via async global->LDS ----
  // 4 ops/wave (8 waves x 4 x 64 lanes x 16 B = 32 KiB), issued FIRST.
  {
    const unsigned short* gw = wsrc + (size_t)d * 16384;
    typedef const __attribute__((address_space(1))) unsigned int* gas_u32;
    typedef __attribute__((address_space(3))) unsigned int* las_u32;
#pragma unroll
    for (int r = 0; r < 4; ++r) {
      const int slotbase = (wave * 4 + r) * 64;
      __builtin_amdgcn_global_load_lds(
          (gas_u32)(const void*)(gw + (size_t)(slotbase + lane) * 8),
          (las_u32)(void*)(wlds + (size_t)slotbase * 8),
          16, 0, 0);
    }
    if (t < 32) {  // lanes 0..31 -> blds[0..127], 16B/lane
      __builtin_amdgcn_global_load_lds(
          (gas_u32)(const void*)(bias + d * 128 + t * 4),
          (las_u32)(void*)(blds), 16, 0, 0);
    }
  }
  __builtin_amdgcn_sched_barrier(0);   // pin W/bias ops oldest in VMEM queue

  // ---- this unit's X loads into registers (stay in flight across barrier)
  float4 pf[8];
  {
    const float* xr = x + ((size_t)(u0 * 128 + wave * 16 + lr)) * 128 + lg * 8;
#pragma unroll
    for (int s = 0; s < 4; ++s) {
      pf[2 * s]     = *(const float4*)(xr + s * 32);
      pf[2 * s + 1] = *(const float4*)(xr + s * 32 + 4);
    }
  }

  // ---- barrier that does NOT drain the X loads ----
  // per wave: W(4) [+bias(1) on wave0] then pf(8). vmcnt(8) drains W+bias.
  asm volatile("s_waitcnt vmcnt(8)" ::: "memory");
  __builtin_amdgcn_s_barrier();
  __builtin_amdgcn_sched_barrier(0);   // rule #18 fence

  // ---- convert (compiler waits vmcnt for pf only) ----
  short8 xf[4];
#pragma unroll
  for (int s = 0; s < 4; ++s) {
    float4 a0 = pf[2 * s], a1 = pf[2 * s + 1];
    u32x4 w;
    w.x = pack_bf2(a0.x, a0.y);
    w.y = pack_bf2(a0.z, a0.w);
    w.z = pack_bf2(a1.x, a1.y);
    w.w = pack_bf2(a1.z, a1.w);
    xf[s] = __builtin_bit_cast(short8, w);
  }

  // ---- MFMA + store, nb-outer / s-inner (1 acc vector live) ----
  const int f = u0 * 128 + wave * 16 + lr;
  const unsigned b = (unsigned)f / (unsigned)L;
  const int l = f - (int)b * L;
  float* orow = out + (size_t)b * 10368 + (size_t)(start * 8 + d) * 128
                + (size_t)l * 1024 + lg * 4;
#pragma unroll
  for (int nb = 0; nb < 8; ++nb) {
    f32x4 acc = *(const f32x4*)&blds[nb * 16 + lg * 4];   // bias init (LDS)
#pragma unroll
    for (int s = 0; s < 4; ++s) {
      short8 wf = *(const short8*)
          &wlds[(size_t)((s * 4 + lg) * 128 + nb * 16 + lr) * 8];
      acc = __builtin_amdgcn_mfma_f32_16x16x32_bf16(wf, xf[s], acc, 0, 0, 0);
    }
    *(f32x4*)(orow + nb * 16) = acc;
  }
}

extern "C" void kernel_launch(void* const* d_in, const int* in_sizes, int n_in,
                              void* d_out, int out_size, void* d_ws, size_t ws_size,
                              hipStream_t stream) {
  const float* W = (const float*)d_in[0];
  const float* bias = (const float*)d_in[1];
  XPtrs xp;
  for (int i = 0; i < 17; ++i) xp.p[i] = (const float*)d_in[2 + i];
  float* out = (float*)d_out;
  unsigned short* ws = (unsigned short*)d_ws;   // 17*2048*16 B = 544 KiB

  Bases bb;
  int base = 0;
  for (int i = 0; i < 17; ++i) {
    bb.v[i] = base;
    int L = 9 - ((i < 8) ? (8 - i) : (i - 8));
    base += 64 * L;              // 8192*L rows / 128 rows per block, exact
  }
  bb.v[17] = base;               // 5184 blocks, uniform work

  convert_w_kernel<<<34, 1024, 0, stream>>>(W, ws);
  diag_linear_kernel<<<base, 512, 0, stream>>>(xp, bb, ws, bias, out);
}

// Round 14
// 145.039 us; speedup vs baseline: 1.1589x; 1.0081x over previous
//
#include <hip/hip_runtime.h>
#include <hip/hip_bf16.h>

typedef __attribute__((ext_vector_type(8))) short short8;
typedef __attribute__((ext_vector_type(4))) float f32x4;
typedef __attribute__((ext_vector_type(4))) unsigned int u32x4;

struct XPtrs { const float* p[17]; };
struct Bases { int v[18]; };

__device__ __forceinline__ unsigned short f2bf(float f) {
  unsigned u = __float_as_uint(f);
  return (unsigned short)((u + 0x7fffu + ((u >> 16) & 1u)) >> 16);  // RNE
}

// ---------------- pre-kernel: W fp32 -> bf16, fragment-packed into ws ----
// Per diag d: 2048 slots of 16 B. slot = sg*128 + n  (sg = s*4 + g)
// slot holds W[d][n][k] for k = sg*8 .. sg*8+7 as 8 bf16 (RNE).
// 136 blocks x 256 threads: wide + shallow to shrink the pre-dispatch bubble.
__global__ __launch_bounds__(256) void convert_w_kernel(
    const float* __restrict__ W, unsigned short* __restrict__ ws) {
  const int tid = blockIdx.x * 256 + threadIdx.x;  // 0 .. 17*2048-1
  const int d  = tid >> 11;
  const int s2 = tid & 2047;
  const int sg = s2 >> 7;     // 0..15
  const int n  = s2 & 127;
  const float* src = W + ((size_t)d * 128 + n) * 128 + sg * 8;
  float4 a = *(const float4*)(src);
  float4 b = *(const float4*)(src + 4);
  unsigned u0 = (unsigned)f2bf(a.x) | ((unsigned)f2bf(a.y) << 16);
  unsigned u1 = (unsigned)f2bf(a.z) | ((unsigned)f2bf(a.w) << 16);
  unsigned u2 = (unsigned)f2bf(b.x) | ((unsigned)f2bf(b.y) << 16);
  unsigned u3 = (unsigned)f2bf(b.z) | ((unsigned)f2bf(b.w) << 16);
  *(uint4*)(ws + (size_t)tid * 8) = make_uint4(u0, u1, u2, u3);
}

// pack two fp32 -> u32 of two bf16, round-half-up (cheap; for X)
__device__ __forceinline__ unsigned pack_bf2(float lo, float hi) {
  unsigned rl = __float_as_uint(lo) + 0x8000u;
  unsigned rh = __float_as_uint(hi) + 0x8000u;
  return __builtin_amdgcn_perm(rh, rl, 0x07060302u);  // {rh[31:16], rl[31:16]}
}

// ---------------- main kernel ----------------
// 256 threads = 4 waves. Block owns ONE unit of 64 rows in ONE diagonal
// (CPB=1: minimal work quantum -> smoothest generation turnover).
// Prologue: W (8 global_load_lds/wave, oldest in VMEM queue) + bias, then
// the unit's X loads to registers. Barrier waits vmcnt(8) only -> W+bias
// resident, X still in flight. Then convert -> MFMA -> store, no loop.
__global__ __launch_bounds__(256) void diag_linear_kernel(
    XPtrs xp, Bases bb, const unsigned short* __restrict__ wsrc,
    const float* __restrict__ bias, float* __restrict__ out) {
  const int bid = blockIdx.x;
  int d = 0;
#pragma unroll
  for (int i = 1; i < 17; ++i) d += (bid >= bb.v[i]) ? 1 : 0;
  const int L = 9 - ((d < 8) ? (8 - d) : (d - 8));
  const int start = (d > 8) ? (d - 8) : 0;
  const float* __restrict__ x = xp.p[d];
  const int u0 = bid - bb.v[d];     // unit index (64 rows per unit)

  const int t = threadIdx.x;
  const int lane = t & 63;
  const int wave = t >> 6;       // 0..3
  const int lr = lane & 15;
  const int lg = lane >> 4;

  __shared__ unsigned short wlds[2048 * 8];  // 32 KiB
  __shared__ float blds[128];                // bias

  // ---- stage W[d] (pre-packed bf16) + bias via async global->LDS ----
  // 8 ops/wave (+1 bias on wave 0), issued FIRST (oldest in VMEM queue).
  {
    const unsigned short* gw = wsrc + (size_t)d * 16384;
    typedef const __attribute__((address_space(1))) unsigned int* gas_u32;
    typedef __attribute__((address_space(3))) unsigned int* las_u32;
#pragma unroll
    for (int r = 0; r < 8; ++r) {
      const int slotbase = (wave * 8 + r) * 64;
      __builtin_amdgcn_global_load_lds(
          (gas_u32)(const void*)(gw + (size_t)(slotbase + lane) * 8),
          (las_u32)(void*)(wlds + (size_t)slotbase * 8),
          16, 0, 0);
    }
    if (t < 32) {  // lanes 0..31 -> blds[0..127], 16B/lane
      __builtin_amdgcn_global_load_lds(
          (gas_u32)(const void*)(bias + d * 128 + t * 4),
          (las_u32)(void*)(blds), 16, 0, 0);
    }
  }
  __builtin_amdgcn_sched_barrier(0);   // pin W/bias ops oldest in VMEM queue

  // ---- this unit's X loads into registers (stay in flight across barrier)
  float4 pf[8];
  {
    const float* xr = x + ((size_t)(u0 * 64 + wave * 16 + lr)) * 128 + lg * 8;
#pragma unroll
    for (int s = 0; s < 4; ++s) {
      pf[2 * s]     = *(const float4*)(xr + s * 32);
      pf[2 * s + 1] = *(const float4*)(xr + s * 32 + 4);
    }
  }

  // ---- barrier that does NOT drain the X loads ----
  // wave0: 9 W/bias + 8 pf = 17 outstanding -> vmcnt(8) drains the 9 oldest
  // (W+bias). waves 1-3: 16 outstanding -> drains 8 (W). pf stays in flight.
  asm volatile("s_waitcnt vmcnt(8)" ::: "memory");
  __builtin_amdgcn_s_barrier();
  __builtin_amdgcn_sched_barrier(0);   // rule #18 fence

  // ---- convert (compiler waits vmcnt for pf only) ----
  short8 xf[4];
#pragma unroll
  for (int s = 0; s < 4; ++s) {
    float4 a0 = pf[2 * s], a1 = pf[2 * s + 1];
    u32x4 w;
    w.x = pack_bf2(a0.x, a0.y);
    w.y = pack_bf2(a0.z, a0.w);
    w.z = pack_bf2(a1.x, a1.y);
    w.w = pack_bf2(a1.z, a1.w);
    xf[s] = __builtin_bit_cast(short8, w);
  }

  // ---- MFMA + store, nb-outer / s-inner (1 acc vector live) ----
  const int f = u0 * 64 + wave * 16 + lr;
  const unsigned b = (unsigned)f / (unsigned)L;
  const int l = f - (int)b * L;
  float* orow = out + (size_t)b * 10368 + (size_t)(start * 8 + d) * 128
                + (size_t)l * 1024 + lg * 4;
#pragma unroll
  for (int nb = 0; nb < 8; ++nb) {
    f32x4 acc = *(const f32x4*)&blds[nb * 16 + lg * 4];   // bias init (LDS)
#pragma unroll
    for (int s = 0; s < 4; ++s) {
      short8 wf = *(const short8*)
          &wlds[(size_t)((s * 4 + lg) * 128 + nb * 16 + lr) * 8];
      acc = __builtin_amdgcn_mfma_f32_16x16x32_bf16(wf, xf[s], acc, 0, 0, 0);
    }
    *(f32x4*)(orow + nb * 16) = acc;
  }
}

extern "C" void kernel_launch(void* const* d_in, const int* in_sizes, int n_in,
                              void* d_out, int out_size, void* d_ws, size_t ws_size,
                              hipStream_t stream) {
  const float* W = (const float*)d_in[0];
  const float* bias = (const float*)d_in[1];
  XPtrs xp;
  for (int i = 0; i < 17; ++i) xp.p[i] = (const float*)d_in[2 + i];
  float* out = (float*)d_out;
  unsigned short* ws = (unsigned short*)d_ws;   // 17*2048*16 B = 544 KiB

  Bases bb;
  int base = 0;
  for (int i = 0; i < 17; ++i) {
    bb.v[i] = base;
    int L = 9 - ((i < 8) ? (8 - i) : (i - 8));
    base += 128 * L;             // 8192*L rows / 64 rows per block, exact
  }
  bb.v[17] = base;               // 10368 blocks, uniform work

  convert_w_kernel<<<136, 256, 0, stream>>>(W, ws);
  diag_linear_kernel<<<base, 256, 0, stream>>>(xp, bb, ws, bias, out);
}

// Round 15
// 144.888 us; speedup vs baseline: 1.1601x; 1.0010x over previous
//
#include <hip/hip_runtime.h>
#include <hip/hip_bf16.h>

typedef __attribute__((ext_vector_type(8))) short short8;
typedef __attribute__((ext_vector_type(4))) float f32x4;
typedef __attribute__((ext_vector_type(4))) unsigned int u32x4;

struct XPtrs { const float* p[17]; };
struct Cum { int v[18]; };   // cumulative L: [0,1,3,...,80,81]

__device__ __forceinline__ unsigned short f2bf(float f) {
  unsigned u = __float_as_uint(f);
  return (unsigned short)((u + 0x7fffu + ((u >> 16) & 1u)) >> 16);  // RNE
}

// ---------------- pre-kernel: W fp32 -> bf16, fragment-packed into ws ----
// Per diag d: 2048 slots of 16 B. slot = sg*128 + n  (sg = s*4 + g)
// slot holds W[d][n][k] for k = sg*8 .. sg*8+7 as 8 bf16 (RNE).
__global__ __launch_bounds__(256) void convert_w_kernel(
    const float* __restrict__ W, unsigned short* __restrict__ ws) {
  const int tid = blockIdx.x * 256 + threadIdx.x;  // 0 .. 17*2048-1
  const int d  = tid >> 11;
  const int s2 = tid & 2047;
  const int sg = s2 >> 7;     // 0..15
  const int n  = s2 & 127;
  const float* src = W + ((size_t)d * 128 + n) * 128 + sg * 8;
  float4 a = *(const float4*)(src);
  float4 b = *(const float4*)(src + 4);
  unsigned u0 = (unsigned)f2bf(a.x) | ((unsigned)f2bf(a.y) << 16);
  unsigned u1 = (unsigned)f2bf(a.z) | ((unsigned)f2bf(a.w) << 16);
  unsigned u2 = (unsigned)f2bf(b.x) | ((unsigned)f2bf(b.y) << 16);
  unsigned u3 = (unsigned)f2bf(b.z) | ((unsigned)f2bf(b.w) << 16);
  *(uint4*)(ws + (size_t)tid * 8) = make_uint4(u0, u1, u2, u3);
}

// pack two fp32 -> u32 of two bf16, round-half-up (cheap; for X)
__device__ __forceinline__ unsigned pack_bf2(float lo, float hi) {
  unsigned rl = __float_as_uint(lo) + 0x8000u;
  unsigned rh = __float_as_uint(hi) + 0x8000u;
  return __builtin_amdgcn_perm(rh, rl, 0x07060302u);  // {rh[31:16], rl[31:16]}
}

// ---------------- main kernel ----------------
// 256 threads = 4 waves, ONE 64-row unit per block (R14 body, unchanged).
// GRID REMAP: bid = window*81 + r, window = 64 batches. All 81 position-
// blocks of a window are adjacent in dispatch order -> co-resident blocks
// write a DENSE contiguous ~33 MB output region (DRAM page locality),
// instead of 512B chunks scattered over ~300 MB (diag-major order).
__global__ __launch_bounds__(256) void diag_linear_kernel(
    XPtrs xp, Cum cum, const unsigned short* __restrict__ wsrc,
    const float* __restrict__ bias, float* __restrict__ out) {
  const int bid = blockIdx.x;
  const int w = (int)((unsigned)bid / 81u);   // batch window (64 batches)
  const int r = bid - w * 81;                 // 0..80: unit-within-window
  int d = 0;
#pragma unroll
  for (int i = 1; i < 17; ++i) d += (r >= cum.v[i]) ? 1 : 0;
  const int L = 9 - ((d < 8) ? (8 - d) : (d - 8));
  const int start = (d > 8) ? (d - 8) : 0;
  const float* __restrict__ x = xp.p[d];
  const int u0 = w * L + (r - cum.v[d]);      // unit index (64 rows per unit)

  const int t = threadIdx.x;
  const int lane = t & 63;
  const int wave = t >> 6;       // 0..3
  const int lr = lane & 15;
  const int lg = lane >> 4;

  __shared__ unsigned short wlds[2048 * 8];  // 32 KiB
  __shared__ float blds[128];                // bias

  // ---- stage W[d] (pre-packed bf16) + bias via async global->LDS ----
  // 8 ops/wave (+1 bias on wave 0), issued FIRST (oldest in VMEM queue).
  {
    const unsigned short* gw = wsrc + (size_t)d * 16384;
    typedef const __attribute__((address_space(1))) unsigned int* gas_u32;
    typedef __attribute__((address_space(3))) unsigned int* las_u32;
#pragma unroll
    for (int rr = 0; rr < 8; ++rr) {
      const int slotbase = (wave * 8 + rr) * 64;
      __builtin_amdgcn_global_load_lds(
          (gas_u32)(const void*)(gw + (size_t)(slotbase + lane) * 8),
          (las_u32)(void*)(wlds + (size_t)slotbase * 8),
          16, 0, 0);
    }
    if (t < 32) {  // lanes 0..31 -> blds[0..127], 16B/lane
      __builtin_amdgcn_global_load_lds(
          (gas_u32)(const void*)(bias + d * 128 + t * 4),
          (las_u32)(void*)(blds), 16, 0, 0);
    }
  }
  __builtin_amdgcn_sched_barrier(0);   // pin W/bias ops oldest in VMEM queue

  // ---- this unit's X loads into registers (stay in flight across barrier)
  float4 pf[8];
  {
    const float* xr = x + ((size_t)(u0 * 64 + wave * 16 + lr)) * 128 + lg * 8;
#pragma unroll
    for (int s = 0; s < 4; ++s) {
      pf[2 * s]     = *(const float4*)(xr + s * 32);
      pf[2 * s + 1] = *(const float4*)(xr + s * 32 + 4);
    }
  }

  // ---- barrier that does NOT drain the X loads ----
  // wave0: 9 W/bias + 8 pf outstanding -> vmcnt(8) drains the 9 oldest
  // (W+bias). waves 1-3: 16 outstanding -> drains 8 (W). pf stays in flight.
  asm volatile("s_waitcnt vmcnt(8)" ::: "memory");
  __builtin_amdgcn_s_barrier();
  __builtin_amdgcn_sched_barrier(0);   // rule #18 fence

  // ---- convert (compiler waits vmcnt for pf only) ----
  short8 xf[4];
#pragma unroll
  for (int s = 0; s < 4; ++s) {
    float4 a0 = pf[2 * s], a1 = pf[2 * s + 1];
    u32x4 wv;
    wv.x = pack_bf2(a0.x, a0.y);
    wv.y = pack_bf2(a0.z, a0.w);
    wv.z = pack_bf2(a1.x, a1.y);
    wv.w = pack_bf2(a1.z, a1.w);
    xf[s] = __builtin_bit_cast(short8, wv);
  }

  // ---- MFMA + store, nb-outer / s-inner (1 acc vector live) ----
  const int f = u0 * 64 + wave * 16 + lr;
  const unsigned b = (unsigned)f / (unsigned)L;
  const int l = f - (int)b * L;
  float* orow = out + (size_t)b * 10368 + (size_t)(start * 8 + d) * 128
                + (size_t)l * 1024 + lg * 4;
#pragma unroll
  for (int nb = 0; nb < 8; ++nb) {
    f32x4 acc = *(const f32x4*)&blds[nb * 16 + lg * 4];   // bias init (LDS)
#pragma unroll
    for (int s = 0; s < 4; ++s) {
      short8 wf = *(const short8*)
          &wlds[(size_t)((s * 4 + lg) * 128 + nb * 16 + lr) * 8];
      acc = __builtin_amdgcn_mfma_f32_16x16x32_bf16(wf, xf[s], acc, 0, 0, 0);
    }
    *(f32x4*)(orow + nb * 16) = acc;
  }
}

extern "C" void kernel_launch(void* const* d_in, const int* in_sizes, int n_in,
                              void* d_out, int out_size, void* d_ws, size_t ws_size,
                              hipStream_t stream) {
  const float* W = (const float*)d_in[0];
  const float* bias = (const float*)d_in[1];
  XPtrs xp;
  for (int i = 0; i < 17; ++i) xp.p[i] = (const float*)d_in[2 + i];
  float* out = (float*)d_out;
  unsigned short* ws = (unsigned short*)d_ws;   // 17*2048*16 B = 544 KiB

  Cum cum;
  int base = 0;
  for (int i = 0; i < 17; ++i) {
    cum.v[i] = base;
    int L = 9 - ((i < 8) ? (8 - i) : (i - 8));
    base += L;                   // units per 64-batch window for diag i
  }
  cum.v[17] = base;              // 81 blocks per window

  convert_w_kernel<<<136, 256, 0, stream>>>(W, ws);
  // 128 windows x 81 = 10368 blocks, batch-window-major order
  diag_linear_kernel<<<128 * 81, 256, 0, stream>>>(xp, cum, ws, bias, out);
}